// Round 11
// baseline (166.673 us; speedup 1.0000x reference)
//
#include <hip/hip_runtime.h>
#include <cfloat>
#include <cmath>
#include <stdint.h>

#define NROWS 32768
#define DIM   256
#define KC    1024

typedef short bf16x8 __attribute__((ext_vector_type(8)));
typedef float f32x4  __attribute__((ext_vector_type(4)));
typedef float f32x2  __attribute__((ext_vector_type(2)));

__device__ inline unsigned short f2bf(float f) {
    unsigned u = __float_as_uint(f);
    u = (u + 0x7fffu + ((u >> 16) & 1u)) >> 16;   // RNE
    return (unsigned short)u;
}

// ---------- prep_w: pack w (hi bf16) into MFMA B-frag order + transpose ----------
__global__ __launch_bounds__(256) void prep_w(const float* __restrict__ w,
                                              uint4* __restrict__ wph,
                                              float* __restrict__ wT) {
    const int t = blockIdx.x * 256 + threadIdx.x;   // 0..32767
    const int l = t & 63;
    const int ks = (t >> 6) & 7;
    const int ctg = t >> 9;
    const int c = ctg * 16 + (l & 15);
    const int kbase = ks * 32 + ((l >> 4) << 3);
    union { unsigned short u[8]; uint4 v; } H;
#pragma unroll
    for (int j = 0; j < 8; ++j) {
        float v = w[(size_t)(kbase + j) * KC + c];
        H.u[j] = f2bf(v);
        wT[(size_t)c * DIM + kbase + j] = v;
    }
    wph[t] = H.v;
}

// ---------- wnorm from wT (fp64 + fp32 copy) ----------
__global__ __launch_bounds__(256) void wnorm_kernel(const float* __restrict__ wT,
                                                    double* __restrict__ wnorm64,
                                                    float* __restrict__ wnormf) {
    const int k = blockIdx.x * 256 + threadIdx.x;
    const float* p = wT + (size_t)k * DIM;
    double acc = 0.0;
#pragma unroll 8
    for (int d = 0; d < DIM; ++d) acc += (double)p[d] * (double)p[d];
    wnorm64[k] = acc;
    wnormf[k] = (float)acc;
}

// ---------- kernel A: MFMA screen v4 — no LDS, 32 rows/wave (2 A-sets) ----------
// block = (rowtile rt = bid>>1 [128 rows], part p = bid&1 [512 cols]).
// 4 waves x 32 rows. Each staged B-frag read feeds 2 MFMAs -> B traffic 512 MB.
// No __syncthreads; 512 blocks = exactly 2/CU, single round.
// cand entry per (row,part): 16 ints = [n, k0..k6, s0..s6(bits), pad]
__global__ __launch_bounds__(256, 2) void vq_screen(
    const float* __restrict__ x,
    const char* __restrict__ wph,
    const float* __restrict__ wnormf,
    int* __restrict__ cand)
{
    const int t = threadIdx.x;
    const int l = t & 63;
    const int wv = t >> 6;
    const int p = blockIdx.x & 1;
    const int rt = blockIdx.x >> 1;
    const int r0 = rt * 128 + wv * 32;
    const char* wp = wph + (size_t)p * 262144;   // part base: 32 ctg x 8192 B

    // ---- A fragments: 2 sets x 16 rows x 256 k, hi bf16 ----
    bf16x8 ah0[8], ah1[8];
#pragma unroll
    for (int s = 0; s < 2; ++s) {
        const float* xb = x + (size_t)(r0 + s * 16 + (l & 15)) * DIM + ((l >> 4) << 3);
#pragma unroll
        for (int ks = 0; ks < 8; ++ks) {
            float4 p0 = *(const float4*)(xb + ks * 32);
            float4 p1 = *(const float4*)(xb + ks * 32 + 4);
            float f[8] = {p0.x, p0.y, p0.z, p0.w, p1.x, p1.y, p1.z, p1.w};
            union { unsigned short u[8]; bf16x8 v; } H;
#pragma unroll
            for (int j = 0; j < 8; ++j) H.u[j] = f2bf(f[j]);
            if (s == 0) ah0[ks] = H.v; else ah1[ks] = H.v;
        }
    }

    // top-3 per row-slot (8 slots/lane: set = s>>2, r = s&3)
    float tv0[8], tv1[8], tv2[8];
    int   tk0[8], tk1[8], tk2[8];
#pragma unroll
    for (int s = 0; s < 8; ++s) { tv0[s] = tv1[s] = tv2[s] = FLT_MAX; tk0[s] = tk1[s] = tk2[s] = 0; }

    // ---- col-frag stream: 32 groups of 16 cols, B double-batched ----
    bf16x8 ba[4], bb[4];
    {
        const char* bp0 = wp + l * 16;
#pragma unroll
        for (int i = 0; i < 4; ++i) ba[i] = *(const bf16x8*)(bp0 + i * 1024);
    }

    for (int ctg = 0; ctg < 32; ++ctg) {
        const char* bp = wp + (size_t)ctg * 8192 + l * 16;
#pragma unroll
        for (int i = 0; i < 4; ++i) bb[i] = *(const bf16x8*)(bp + (4 + i) * 1024);

        f32x4 a0 = (f32x4){0.f, 0.f, 0.f, 0.f};
        f32x4 a1 = (f32x4){0.f, 0.f, 0.f, 0.f};
#pragma unroll
        for (int i = 0; i < 4; ++i) {
            a0 = __builtin_amdgcn_mfma_f32_16x16x32_bf16(ah0[i], ba[i], a0, 0, 0, 0);
            a1 = __builtin_amdgcn_mfma_f32_16x16x32_bf16(ah1[i], ba[i], a1, 0, 0, 0);
        }
        if (ctg + 1 < 32) {
            const char* np = wp + (size_t)(ctg + 1) * 8192 + l * 16;
#pragma unroll
            for (int i = 0; i < 4; ++i) ba[i] = *(const bf16x8*)(np + i * 1024);
        }
#pragma unroll
        for (int i = 0; i < 4; ++i) {
            a0 = __builtin_amdgcn_mfma_f32_16x16x32_bf16(ah0[4 + i], bb[i], a0, 0, 0, 0);
            a1 = __builtin_amdgcn_mfma_f32_16x16x32_bf16(ah1[4 + i], bb[i], a1, 0, 0, 0);
        }

        const int k = (p * 32 + ctg) * 16 + (l & 15);
        const float wn = wnormf[k];
#pragma unroll
        for (int s = 0; s < 8; ++s) {
            const float av = (s < 4) ? a0[s & 3] : a1[s & 3];
            float sc = fmaf(-2.0f, av, wn);
            if (sc < tv2[s]) {
                if (sc < tv1[s]) {
                    tv2[s] = tv1[s]; tk2[s] = tk1[s];
                    if (sc < tv0[s]) { tv1[s] = tv0[s]; tk1[s] = tk0[s]; tv0[s] = sc; tk0[s] = k; }
                    else             { tv1[s] = sc;     tk1[s] = k; }
                } else { tv2[s] = sc; tk2[s] = k; }
            }
        }
    }

    // ---- per-slot part-local rowmin + ballot-compacted (k, score) write ----
    const float margin = 0.125f;
    const int grpShift = (l >> 4) * 16;
    const unsigned laneMask = (1u << (l & 15)) - 1u;
#pragma unroll
    for (int s = 0; s < 8; ++s) {
        float v = tv0[s];
#pragma unroll
        for (int m = 1; m <= 8; m <<= 1) v = fminf(v, __shfl_xor(v, m));
        const float thr = v + margin;
        const int row = r0 + (s >> 2) * 16 + ((l >> 4) << 2) + (s & 3);
        int* creg = cand + ((size_t)row * 2 + p) * 16;
        int base = 0;
        {
            bool c = tv0[s] <= thr;
            unsigned long long bal = __ballot(c);
            unsigned grp = (unsigned)(bal >> grpShift) & 0xFFFFu;
            int pos = base + __popc(grp & laneMask);
            if (c && pos < 7) { creg[1 + pos] = tk0[s]; creg[8 + pos] = __float_as_int(tv0[s]); }
            base += __popc(grp);
        }
        {
            bool c = tv1[s] <= thr;
            unsigned long long bal = __ballot(c);
            unsigned grp = (unsigned)(bal >> grpShift) & 0xFFFFu;
            int pos = base + __popc(grp & laneMask);
            if (c && pos < 7) { creg[1 + pos] = tk1[s]; creg[8 + pos] = __float_as_int(tv1[s]); }
            base += __popc(grp);
        }
        {
            bool c = tv2[s] <= thr;
            unsigned long long bal = __ballot(c);
            unsigned grp = (unsigned)(bal >> grpShift) & 0xFFFFu;
            int pos = base + __popc(grp & laneMask);
            if (c && pos < 7) { creg[1 + pos] = tk2[s]; creg[8 + pos] = __float_as_int(tv2[s]); }
            base += __popc(grp);
        }
        if ((l & 15) == 0) creg[0] = base < 7 ? base : 7;
    }
}

// ---------- kernel B: select (usually free) + rare fp64 refine + epilogue ----------
__global__ __launch_bounds__(256) void vq_final(
    const float* __restrict__ x, const float* __restrict__ wT,
    const double* __restrict__ wnorm64,
    const int* __restrict__ cand,
    float* __restrict__ out_q, float* __restrict__ out_idx, float* __restrict__ out_enc,
    int* __restrict__ counts, double* __restrict__ loss_sum)
{
    const int t = threadIdx.x;
    const int l = t & 63;
    const int wv = t >> 6;
    __shared__ double wsum[4];
    const float margin = 0.125f;

    double ls0 = 0.0, ls1 = 0.0, ls2 = 0.0, ls3 = 0.0;
    const int stride = gridDim.x * 4;
    for (int row = blockIdx.x * 4 + wv; row < NROWS; row += stride) {
        const float4 xv = ((const float4*)(x + (size_t)row * DIM))[l];
        const int* c0 = cand + (size_t)row * 32;

        // global screen min over stored candidate scores
        float m = FLT_MAX;
#pragma unroll
        for (int p2 = 0; p2 < 2; ++p2) {
            const int* cp = c0 + p2 * 16;
            const int n = cp[0];
            for (int c = 0; c < n; ++c) m = fminf(m, __int_as_float(cp[8 + c]));
        }
        const float thr = m + margin;

        // count qualifiers; single qualifier IS the argmin (margin covers screen err)
        int bk = 0x7FFFFFFF, cnt = 0;
#pragma unroll
        for (int p2 = 0; p2 < 2; ++p2) {
            const int* cp = c0 + p2 * 16;
            const int n = cp[0];
            for (int c = 0; c < n; ++c)
                if (__int_as_float(cp[8 + c]) <= thr) { ++cnt; bk = cp[1 + c]; }
        }
        if (cnt > 1) {
            double best = 1e300; bk = 0x7FFFFFFF;
#pragma unroll
            for (int p2 = 0; p2 < 2; ++p2) {
                const int* cp = c0 + p2 * 16;
                const int n = cp[0];
                for (int c = 0; c < n; ++c) {
                    if (__int_as_float(cp[8 + c]) > thr) continue;
                    const int k2 = cp[1 + c];
                    const float4 w4 = ((const float4*)(wT + (size_t)k2 * DIM))[l];
                    double d = (double)xv.x * (double)w4.x;
                    d = fma((double)xv.y, (double)w4.y, d);
                    d = fma((double)xv.z, (double)w4.z, d);
                    d = fma((double)xv.w, (double)w4.w, d);
#pragma unroll
                    for (int mm = 32; mm > 0; mm >>= 1) d += __shfl_xor(d, mm);
                    const double s64 = wnorm64[k2] - 2.0 * d;
                    if (s64 < best || (s64 == best && k2 < bk)) { best = s64; bk = k2; }
                }
            }
        }
        const int k = __builtin_amdgcn_readfirstlane(bk);

        const float4 qv = ((const float4*)(wT + (size_t)k * DIM))[l];
        f32x4 o = {xv.x + (qv.x - xv.x), xv.y + (qv.y - xv.y),
                   xv.z + (qv.z - xv.z), xv.w + (qv.w - xv.w)};
        __builtin_nontemporal_store(o, (f32x4*)(out_q + (size_t)row * DIM) + l);
        double dx = (double)qv.x - (double)xv.x; ls0 = fma(dx, dx, ls0);
        dx = (double)qv.y - (double)xv.y; ls1 = fma(dx, dx, ls1);
        dx = (double)qv.z - (double)xv.z; ls2 = fma(dx, dx, ls2);
        dx = (double)qv.w - (double)xv.w; ls3 = fma(dx, dx, ls3);
        // one-hot zeros: coalesced f32x2 stores (512 contiguous B / instr)
        f32x2* er2 = (f32x2*)(out_enc + (size_t)row * KC);
        f32x2 z = {0.f, 0.f};
#pragma unroll
        for (int i = 0; i < 8; ++i)
            __builtin_nontemporal_store(z, er2 + i * 64 + l);
        // the 1.0: same lane that wrote the covering f32x2 (program order)
        if (l == ((k >> 1) & 63)) out_enc[(size_t)row * KC + k] = 1.0f;
        if (l == 0) {
            out_idx[row] = (float)k;
            atomicAdd(&counts[k], 1);
        }
    }
    double lsum = (ls0 + ls1) + (ls2 + ls3);
#pragma unroll
    for (int off = 32; off > 0; off >>= 1) lsum += __shfl_down(lsum, off);
    if (l == 0) wsum[wv] = lsum;
    __syncthreads();
    if (t == 0) atomicAdd(loss_sum, wsum[0] + wsum[1] + wsum[2] + wsum[3]);
}

// ---------- finalize ----------
__global__ __launch_bounds__(1024) void final_kernel(const int* __restrict__ counts,
                                                     const double* __restrict__ loss_sum,
                                                     float* __restrict__ out_loss,
                                                     float* __restrict__ out_ppl) {
    const int t = threadIdx.x;
    double p = (double)counts[t] * (1.0 / 32768.0);
    double term = -p * log(p + 1e-10);
#pragma unroll
    for (int off = 32; off > 0; off >>= 1) term += __shfl_down(term, off);
    __shared__ double ws[16];
    if ((t & 63) == 0) ws[t >> 6] = term;
    __syncthreads();
    if (t == 0) {
        double s = 0.0;
        for (int i = 0; i < 16; ++i) s += ws[i];
        *out_ppl = (float)exp(s);
        *out_loss = (float)(1.25 * loss_sum[0] * (1.0 / 8388608.0));
    }
}

extern "C" void kernel_launch(void* const* d_in, const int* in_sizes, int n_in,
                              void* d_out, int out_size, void* d_ws, size_t ws_size,
                              hipStream_t stream) {
    const float* x = (const float*)d_in[0];   // [32,32,32,256] fp32
    const float* w = (const float*)d_in[1];   // [256,1024] fp32

    float* out = (float*)d_out;
    float* out_q    = out;                        // 8388608
    float* out_loss = out + 8388608;              // 1
    float* out_ppl  = out + 8388609;              // 1
    float* out_enc  = out + 8388610;              // 33554432
    float* out_idx  = out + 8388610 + 33554432;   // 32768

    char* wsb = (char*)d_ws;
    double* loss_sum = (double*)(wsb + 0);
    int*    counts   = (int*)(wsb + 64);          // 4096 B
    double* wnorm64  = (double*)(wsb + 4160);     // 8192 B
    float*  wnormf   = (float*)(wsb + 12352);     // 4096 B
    float*  wT       = (float*)(wsb + 16448);     // 1 MB
    uint4*  wph      = (uint4*)(wsb + 1065024);   // 512 KB
    int*    cand     = (int*)(wsb + 1589312);     // 4 MB candidate lists

    (void)hipMemsetAsync(d_ws, 0, 4160, stream);  // loss_sum + counts

    prep_w<<<128, 256, 0, stream>>>(w, wph, wT);
    wnorm_kernel<<<4, 256, 0, stream>>>(wT, wnorm64, wnormf);
    vq_screen<<<512, 256, 0, stream>>>(x, (const char*)wph, wnormf, cand);
    vq_final<<<2048, 256, 0, stream>>>(x, wT, wnorm64, cand,
                                       out_q, out_idx, out_enc, counts, loss_sum);
    final_kernel<<<1, 1024, 0, stream>>>(counts, loss_sum, out_loss, out_ppl);
}

// Round 12
// 143.100 us; speedup vs baseline: 1.1647x; 1.1647x over previous
//
#include <hip/hip_runtime.h>
#include <cfloat>
#include <cmath>
#include <stdint.h>

#define NROWS 32768
#define DIM   256
#define KC    1024

typedef short bf16x8 __attribute__((ext_vector_type(8)));
typedef float f32x4  __attribute__((ext_vector_type(4)));
typedef float f32x2  __attribute__((ext_vector_type(2)));

__device__ inline unsigned short f2bf(float f) {
    unsigned u = __float_as_uint(f);
    u = (u + 0x7fffu + ((u >> 16) & 1u)) >> 16;   // RNE
    return (unsigned short)u;
}

// ---------- prep_w: pack w (hi bf16) into MFMA B-frag order, x4 copies + transpose ----------
__global__ __launch_bounds__(256) void prep_w(const float* __restrict__ w,
                                              uint4* __restrict__ wph,
                                              float* __restrict__ wT) {
    const int t = blockIdx.x * 256 + threadIdx.x;   // 0..32767
    const int l = t & 63;
    const int ks = (t >> 6) & 7;
    const int ctg = t >> 9;
    const int c = ctg * 16 + (l & 15);
    const int kbase = ks * 32 + ((l >> 4) << 3);
    union { unsigned short u[8]; uint4 v; } H;
#pragma unroll
    for (int j = 0; j < 8; ++j) {
        float v = w[(size_t)(kbase + j) * KC + c];
        H.u[j] = f2bf(v);
        wT[(size_t)c * DIM + kbase + j] = v;
    }
    // 4 replicas to spread same-line L2 traffic
#pragma unroll
    for (int cp = 0; cp < 4; ++cp)
        wph[cp * 32768 + t] = H.v;
}

// ---------- wnorm from wT (fp64 + fp32 copy) ----------
__global__ __launch_bounds__(256) void wnorm_kernel(const float* __restrict__ wT,
                                                    double* __restrict__ wnorm64,
                                                    float* __restrict__ wnormf) {
    const int k = blockIdx.x * 256 + threadIdx.x;
    const float* p = wT + (size_t)k * DIM;
    double acc = 0.0;
#pragma unroll 8
    for (int d = 0; d < DIM; ++d) acc += (double)p[d] * (double)p[d];
    wnorm64[k] = acc;
    wnormf[k] = (float)acc;
}

// ---------- kernel A: MFMA screen v5 — no LDS, staggered sweep + replicated B ----------
// block = (rowtile rt = bid>>1 [64 rows], part p = bid&1 [512 cols]).
// Each block starts its 32-ctg sweep at a different offset (decorrelates the
// window every block reads at a given instant) and uses 1 of 4 B replicas
// (cuts same-128B-line concurrent readers ~128x vs R10).
__global__ __launch_bounds__(256, 4) void vq_screen(
    const float* __restrict__ x,
    const char* __restrict__ wph,
    const float* __restrict__ wnormf,
    int* __restrict__ cand)
{
    const int t = threadIdx.x;
    const int l = t & 63;
    const int wv = t >> 6;
    const int p = blockIdx.x & 1;
    const int rt = blockIdx.x >> 1;
    const int r0 = rt * 64 + wv * 16;
    const int cpy = (blockIdx.x >> 3) & 3;
    const int off = (blockIdx.x >> 1) & 31;
    const char* wp = wph + (size_t)cpy * 524288 + (size_t)p * 262144;

    // ---- A fragments: 16 rows x 256 k, hi bf16, converted in-register ----
    bf16x8 ah[8];
    {
        const float* xb = x + (size_t)(r0 + (l & 15)) * DIM + ((l >> 4) << 3);
#pragma unroll
        for (int ks = 0; ks < 8; ++ks) {
            float4 p0 = *(const float4*)(xb + ks * 32);
            float4 p1 = *(const float4*)(xb + ks * 32 + 4);
            float f[8] = {p0.x, p0.y, p0.z, p0.w, p1.x, p1.y, p1.z, p1.w};
            union { unsigned short u[8]; bf16x8 v; } H;
#pragma unroll
            for (int j = 0; j < 8; ++j) H.u[j] = f2bf(f[j]);
            ah[ks] = H.v;
        }
    }

    // top-3 per row-slot (4 slots/lane)
    float tv0[4], tv1[4], tv2[4];
    int   tk0[4], tk1[4], tk2[4];
#pragma unroll
    for (int r = 0; r < 4; ++r) { tv0[r] = tv1[r] = tv2[r] = FLT_MAX; tk0[r] = tk1[r] = tk2[r] = 0; }

    // ---- col-frag stream: 32 groups of 16 cols, staggered start ----
#pragma unroll 2
    for (int cg0 = 0; cg0 < 32; ++cg0) {
        const int ctg = (cg0 + off) & 31;
        const char* bp = wp + (size_t)ctg * 8192 + l * 16;
        bf16x8 b[8];
#pragma unroll
        for (int ks = 0; ks < 8; ++ks)
            b[ks] = *(const bf16x8*)(bp + ks * 1024);

        f32x4 acc = (f32x4){0.f, 0.f, 0.f, 0.f};
#pragma unroll
        for (int ks = 0; ks < 8; ++ks)
            acc = __builtin_amdgcn_mfma_f32_16x16x32_bf16(ah[ks], b[ks], acc, 0, 0, 0);

        const int k = (p * 32 + ctg) * 16 + (l & 15);
        const float wn = wnormf[k];
#pragma unroll
        for (int r = 0; r < 4; ++r) {
            float sc = fmaf(-2.0f, acc[r], wn);
            if (sc < tv2[r]) {
                if (sc < tv1[r]) {
                    tv2[r] = tv1[r]; tk2[r] = tk1[r];
                    if (sc < tv0[r]) { tv1[r] = tv0[r]; tk1[r] = tk0[r]; tv0[r] = sc; tk0[r] = k; }
                    else             { tv1[r] = sc;     tk1[r] = k; }
                } else { tv2[r] = sc; tk2[r] = k; }
            }
        }
    }

    // ---- per-slot part-local rowmin + ballot-compacted (k, score) write ----
    const float margin = 0.125f;
    const int grpShift = (l >> 4) * 16;
    const unsigned laneMask = (1u << (l & 15)) - 1u;
#pragma unroll
    for (int r = 0; r < 4; ++r) {
        float v = tv0[r];
#pragma unroll
        for (int m = 1; m <= 8; m <<= 1) v = fminf(v, __shfl_xor(v, m));
        const float thr = v + margin;
        const int row = r0 + ((l >> 4) << 2) + r;
        int* creg = cand + ((size_t)row * 2 + p) * 16;
        int base = 0;
        {
            bool c = tv0[r] <= thr;
            unsigned long long bal = __ballot(c);
            unsigned grp = (unsigned)(bal >> grpShift) & 0xFFFFu;
            int pos = base + __popc(grp & laneMask);
            if (c && pos < 7) { creg[1 + pos] = tk0[r]; creg[8 + pos] = __float_as_int(tv0[r]); }
            base += __popc(grp);
        }
        {
            bool c = tv1[r] <= thr;
            unsigned long long bal = __ballot(c);
            unsigned grp = (unsigned)(bal >> grpShift) & 0xFFFFu;
            int pos = base + __popc(grp & laneMask);
            if (c && pos < 7) { creg[1 + pos] = tk1[r]; creg[8 + pos] = __float_as_int(tv1[r]); }
            base += __popc(grp);
        }
        {
            bool c = tv2[r] <= thr;
            unsigned long long bal = __ballot(c);
            unsigned grp = (unsigned)(bal >> grpShift) & 0xFFFFu;
            int pos = base + __popc(grp & laneMask);
            if (c && pos < 7) { creg[1 + pos] = tk2[r]; creg[8 + pos] = __float_as_int(tv2[r]); }
            base += __popc(grp);
        }
        if ((l & 15) == 0) creg[0] = base < 7 ? base : 7;
    }
}

// ---------- kernel B: select (usually free) + rare fp64 refine + epilogue ----------
__global__ __launch_bounds__(256) void vq_final(
    const float* __restrict__ x, const float* __restrict__ wT,
    const double* __restrict__ wnorm64,
    const int* __restrict__ cand,
    float* __restrict__ out_q, float* __restrict__ out_idx, float* __restrict__ out_enc,
    int* __restrict__ counts, double* __restrict__ loss_sum)
{
    const int t = threadIdx.x;
    const int l = t & 63;
    const int wv = t >> 6;
    __shared__ double wsum[4];
    const float margin = 0.125f;

    double ls0 = 0.0, ls1 = 0.0, ls2 = 0.0, ls3 = 0.0;
    const int stride = gridDim.x * 4;
    for (int row = blockIdx.x * 4 + wv; row < NROWS; row += stride) {
        const float4 xv = ((const float4*)(x + (size_t)row * DIM))[l];
        const int* c0 = cand + (size_t)row * 32;

        // global screen min over stored candidate scores
        float m = FLT_MAX;
#pragma unroll
        for (int p2 = 0; p2 < 2; ++p2) {
            const int* cp = c0 + p2 * 16;
            const int n = cp[0];
            for (int c = 0; c < n; ++c) m = fminf(m, __int_as_float(cp[8 + c]));
        }
        const float thr = m + margin;

        // count qualifiers; single qualifier IS the argmin (margin covers screen err)
        int bk = 0x7FFFFFFF, cnt = 0;
#pragma unroll
        for (int p2 = 0; p2 < 2; ++p2) {
            const int* cp = c0 + p2 * 16;
            const int n = cp[0];
            for (int c = 0; c < n; ++c)
                if (__int_as_float(cp[8 + c]) <= thr) { ++cnt; bk = cp[1 + c]; }
        }
        if (cnt > 1) {
            double best = 1e300; bk = 0x7FFFFFFF;
#pragma unroll
            for (int p2 = 0; p2 < 2; ++p2) {
                const int* cp = c0 + p2 * 16;
                const int n = cp[0];
                for (int c = 0; c < n; ++c) {
                    if (__int_as_float(cp[8 + c]) > thr) continue;
                    const int k2 = cp[1 + c];
                    const float4 w4 = ((const float4*)(wT + (size_t)k2 * DIM))[l];
                    double d = (double)xv.x * (double)w4.x;
                    d = fma((double)xv.y, (double)w4.y, d);
                    d = fma((double)xv.z, (double)w4.z, d);
                    d = fma((double)xv.w, (double)w4.w, d);
#pragma unroll
                    for (int mm = 32; mm > 0; mm >>= 1) d += __shfl_xor(d, mm);
                    const double s64 = wnorm64[k2] - 2.0 * d;
                    if (s64 < best || (s64 == best && k2 < bk)) { best = s64; bk = k2; }
                }
            }
        }
        const int k = __builtin_amdgcn_readfirstlane(bk);

        const float4 qv = ((const float4*)(wT + (size_t)k * DIM))[l];
        f32x4 o = {xv.x + (qv.x - xv.x), xv.y + (qv.y - xv.y),
                   xv.z + (qv.z - xv.z), xv.w + (qv.w - xv.w)};
        __builtin_nontemporal_store(o, (f32x4*)(out_q + (size_t)row * DIM) + l);
        double dx = (double)qv.x - (double)xv.x; ls0 = fma(dx, dx, ls0);
        dx = (double)qv.y - (double)xv.y; ls1 = fma(dx, dx, ls1);
        dx = (double)qv.z - (double)xv.z; ls2 = fma(dx, dx, ls2);
        dx = (double)qv.w - (double)xv.w; ls3 = fma(dx, dx, ls3);
        // one-hot zeros: coalesced f32x2 stores (512 contiguous B / instr)
        f32x2* er2 = (f32x2*)(out_enc + (size_t)row * KC);
        f32x2 z = {0.f, 0.f};
#pragma unroll
        for (int i = 0; i < 8; ++i)
            __builtin_nontemporal_store(z, er2 + i * 64 + l);
        // the 1.0: same lane that wrote the covering f32x2 (program order)
        if (l == ((k >> 1) & 63)) out_enc[(size_t)row * KC + k] = 1.0f;
        if (l == 0) {
            out_idx[row] = (float)k;
            atomicAdd(&counts[k], 1);
        }
    }
    double lsum = (ls0 + ls1) + (ls2 + ls3);
#pragma unroll
    for (int off = 32; off > 0; off >>= 1) lsum += __shfl_down(lsum, off);
    if (l == 0) wsum[wv] = lsum;
    __syncthreads();
    if (t == 0) atomicAdd(loss_sum, wsum[0] + wsum[1] + wsum[2] + wsum[3]);
}

// ---------- finalize ----------
__global__ __launch_bounds__(1024) void final_kernel(const int* __restrict__ counts,
                                                     const double* __restrict__ loss_sum,
                                                     float* __restrict__ out_loss,
                                                     float* __restrict__ out_ppl) {
    const int t = threadIdx.x;
    double p = (double)counts[t] * (1.0 / 32768.0);
    double term = -p * log(p + 1e-10);
#pragma unroll
    for (int off = 32; off > 0; off >>= 1) term += __shfl_down(term, off);
    __shared__ double ws[16];
    if ((t & 63) == 0) ws[t >> 6] = term;
    __syncthreads();
    if (t == 0) {
        double s = 0.0;
        for (int i = 0; i < 16; ++i) s += ws[i];
        *out_ppl = (float)exp(s);
        *out_loss = (float)(1.25 * loss_sum[0] * (1.0 / 8388608.0));
    }
}

extern "C" void kernel_launch(void* const* d_in, const int* in_sizes, int n_in,
                              void* d_out, int out_size, void* d_ws, size_t ws_size,
                              hipStream_t stream) {
    const float* x = (const float*)d_in[0];   // [32,32,32,256] fp32
    const float* w = (const float*)d_in[1];   // [256,1024] fp32

    float* out = (float*)d_out;
    float* out_q    = out;                        // 8388608
    float* out_loss = out + 8388608;              // 1
    float* out_ppl  = out + 8388609;              // 1
    float* out_enc  = out + 8388610;              // 33554432
    float* out_idx  = out + 8388610 + 33554432;   // 32768

    char* wsb = (char*)d_ws;
    double* loss_sum = (double*)(wsb + 0);
    int*    counts   = (int*)(wsb + 64);          // 4096 B
    double* wnorm64  = (double*)(wsb + 4160);     // 8192 B
    float*  wnormf   = (float*)(wsb + 12352);     // 4096 B
    float*  wT       = (float*)(wsb + 16448);     // 1 MB
    uint4*  wph      = (uint4*)(wsb + 1065024);   // 2 MB (4 replicas x 512 KB)
    int*    cand     = (int*)(wsb + 3162176);     // 4 MB candidate lists

    (void)hipMemsetAsync(d_ws, 0, 4160, stream);  // loss_sum + counts

    prep_w<<<128, 256, 0, stream>>>(w, wph, wT);
    wnorm_kernel<<<4, 256, 0, stream>>>(wT, wnorm64, wnormf);
    vq_screen<<<1024, 256, 0, stream>>>(x, (const char*)wph, wnormf, cand);
    vq_final<<<2048, 256, 0, stream>>>(x, wT, wnorm64, cand,
                                       out_q, out_idx, out_enc, counts, loss_sum);
    final_kernel<<<1, 1024, 0, stream>>>(counts, loss_sum, out_loss, out_ppl);
}

// Round 13
// 140.507 us; speedup vs baseline: 1.1862x; 1.0185x over previous
//
#include <hip/hip_runtime.h>
#include <cfloat>
#include <cmath>
#include <stdint.h>

#define NROWS 32768
#define DIM   256
#define KC    1024

typedef short bf16x8 __attribute__((ext_vector_type(8)));
typedef float f32x4  __attribute__((ext_vector_type(4)));
typedef float f32x2  __attribute__((ext_vector_type(2)));

__device__ inline unsigned short f2bf(float f) {
    unsigned u = __float_as_uint(f);
    u = (u + 0x7fffu + ((u >> 16) & 1u)) >> 16;   // RNE
    return (unsigned short)u;
}

// ---------- prep_w: pack w (hi bf16) into MFMA B-frag order + transpose ----------
__global__ __launch_bounds__(256) void prep_w(const float* __restrict__ w,
                                              uint4* __restrict__ wph,
                                              float* __restrict__ wT) {
    const int t = blockIdx.x * 256 + threadIdx.x;   // 0..32767
    const int l = t & 63;
    const int ks = (t >> 6) & 7;
    const int ctg = t >> 9;
    const int c = ctg * 16 + (l & 15);
    const int kbase = ks * 32 + ((l >> 4) << 3);
    union { unsigned short u[8]; uint4 v; } H;
#pragma unroll
    for (int j = 0; j < 8; ++j) {
        float v = w[(size_t)(kbase + j) * KC + c];
        H.u[j] = f2bf(v);
        wT[(size_t)c * DIM + kbase + j] = v;
    }
    wph[t] = H.v;
}

// ---------- wnorm from wT (fp64 + fp32 copy) ----------
__global__ __launch_bounds__(256) void wnorm_kernel(const float* __restrict__ wT,
                                                    double* __restrict__ wnorm64,
                                                    float* __restrict__ wnormf) {
    const int k = blockIdx.x * 256 + threadIdx.x;
    const float* p = wT + (size_t)k * DIM;
    double acc = 0.0;
#pragma unroll 8
    for (int d = 0; d < DIM; ++d) acc += (double)p[d] * (double)p[d];
    wnorm64[k] = acc;
    wnormf[k] = (float)acc;
}

// ---------- fused kernel: screen (block-shared B staging) + select + epilogue ----------
// 256 blocks x 512 threads (8 waves x 16 rows = 128 rows/block, 1 block/CU).
// B staged ONCE per block: 32 groups x 16KB, double-buffered, shared by 8 waves
// -> per-CU global B traffic 512KB (8x less than the no-LDS variant).
__global__ __launch_bounds__(512, 2) void vq_fused(
    const float* __restrict__ x,
    const char* __restrict__ wph,
    const float* __restrict__ wT,
    const double* __restrict__ wnorm64, const float* __restrict__ wnormf,
    float* __restrict__ out_q, float* __restrict__ out_idx, float* __restrict__ out_enc,
    int* __restrict__ counts, double* __restrict__ loss_sum)
{
    __shared__ char ldsbuf[32768];   // 2 x 16KB double buffer
    __shared__ double wsum[8];

    const int t = threadIdx.x;
    const int l = t & 63;
    const int wv = t >> 6;           // 0..7
    const int r0 = blockIdx.x * 128 + wv * 16;

    // ---- A fragments: 16 rows x 256 k, hi bf16, converted in-register ----
    bf16x8 ah[8];
    {
        const float* xb = x + (size_t)(r0 + (l & 15)) * DIM + ((l >> 4) << 3);
#pragma unroll
        for (int ks = 0; ks < 8; ++ks) {
            float4 p0 = *(const float4*)(xb + ks * 32);
            float4 p1 = *(const float4*)(xb + ks * 32 + 4);
            float f[8] = {p0.x, p0.y, p0.z, p0.w, p1.x, p1.y, p1.z, p1.w};
            union { unsigned short u[8]; bf16x8 v; } H;
#pragma unroll
            for (int j = 0; j < 8; ++j) H.u[j] = f2bf(f[j]);
            ah[ks] = H.v;
        }
    }

    // top-3 per row-slot (4 slots/lane)
    float tv0[4], tv1[4], tv2[4];
    int   tk0[4], tk1[4], tk2[4];
#pragma unroll
    for (int r = 0; r < 4; ++r) { tv0[r] = tv1[r] = tv2[r] = FLT_MAX; tk0[r] = tk1[r] = tk2[r] = 0; }

    // ---- K-loop: 32 groups of 32 cols (16KB), block-staged, double-buffered ----
    {
        const char* g0 = wph + wv * 2048 + l * 16;
        char* d0 = ldsbuf + wv * 2048 + l * 16;
#pragma unroll
        for (int i = 0; i < 2; ++i)
            __builtin_amdgcn_global_load_lds(
                (const __attribute__((address_space(1))) void*)(g0 + i * 1024),
                (__attribute__((address_space(3))) void*)(d0 + i * 1024), 16, 0, 0);
    }
    __syncthreads();

    int cur = 0;
    for (int g = 0; g < 32; ++g) {
        if (g + 1 < 32) {   // prefetch next group into other buffer (shared by block)
            const char* gp = wph + (size_t)(g + 1) * 16384 + wv * 2048 + l * 16;
            char* dp = ldsbuf + (cur ^ 1) * 16384 + wv * 2048 + l * 16;
#pragma unroll
            for (int i = 0; i < 2; ++i)
                __builtin_amdgcn_global_load_lds(
                    (const __attribute__((address_space(1))) void*)(gp + i * 1024),
                    (__attribute__((address_space(3))) void*)(dp + i * 1024), 16, 0, 0);
        }

#pragma unroll
        for (int ctg2 = 0; ctg2 < 2; ++ctg2) {
            f32x4 acc = (f32x4){0.f, 0.f, 0.f, 0.f};
#pragma unroll
            for (int ks = 0; ks < 8; ++ks) {
                bf16x8 b = *(const bf16x8*)(ldsbuf + cur * 16384 + ctg2 * 8192 + ks * 1024 + l * 16);
                acc = __builtin_amdgcn_mfma_f32_16x16x32_bf16(ah[ks], b, acc, 0, 0, 0);
            }
            const int k = (g * 2 + ctg2) * 16 + (l & 15);
            const float wn = wnormf[k];
#pragma unroll
            for (int r = 0; r < 4; ++r) {
                float sc = fmaf(-2.0f, acc[r], wn);
                if (sc < tv2[r]) {
                    if (sc < tv1[r]) {
                        tv2[r] = tv1[r]; tk2[r] = tk1[r];
                        if (sc < tv0[r]) { tv1[r] = tv0[r]; tk1[r] = tk0[r]; tv0[r] = sc; tk0[r] = k; }
                        else             { tv1[r] = sc;     tk1[r] = k; }
                    } else { tv2[r] = sc; tk2[r] = k; }
                }
            }
        }

        __syncthreads();   // drains prefetch + guards buffer swap
        cur ^= 1;
    }

    // ---- in-wave select per row: fast path from screen scores, rare fp64 refine ----
    const float margin = 0.125f;
    const int grpShift = (l >> 4) * 16;
    int bestk[4];
#pragma unroll
    for (int r = 0; r < 4; ++r) {
        float v = tv0[r];
#pragma unroll
        for (int m = 1; m <= 8; m <<= 1) v = fminf(v, __shfl_xor(v, m));
        const float thr = v + margin;

        unsigned long long b0 = __ballot(tv0[r] <= thr);
        unsigned long long b1 = __ballot(tv1[r] <= thr);
        unsigned long long b2 = __ballot(tv2[r] <= thr);
        unsigned g0 = (unsigned)(b0 >> grpShift) & 0xFFFFu;
        unsigned g1 = (unsigned)(b1 >> grpShift) & 0xFFFFu;
        unsigned g2 = (unsigned)(b2 >> grpShift) & 0xFFFFu;
        const int cnt = __popc(g0) + __popc(g1) + __popc(g2);

        int k;
        if (cnt == 1) {
            // the single qualifier is tv0's min holder (min always qualifies)
            k = __shfl(tk0[r], grpShift + (31 - __clz(g0)));
        } else {
            // fp64 refine across this 16-lane group's candidates
            const int row = r0 + ((l >> 4) << 2) + r;
            const float4* x4 = (const float4*)(x + (size_t)row * DIM);
            double best = 1e300; int bk = 0x7FFFFFFF;
#pragma unroll
            for (int j = 0; j < 3; ++j) {
                unsigned gj = (j == 0) ? g0 : (j == 1) ? g1 : g2;
                const int tkj = (j == 0) ? tk0[r] : (j == 1) ? tk1[r] : tk2[r];
                while (gj) {
                    const int c = __ffs(gj) - 1;
                    gj &= gj - 1;
                    const int k2 = __shfl(tkj, grpShift + c);
                    const float4* w4 = (const float4*)(wT + (size_t)k2 * DIM);
                    double d = 0.0;
#pragma unroll
                    for (int i = 0; i < 4; ++i) {
                        const int idx = (l & 15) + 16 * i;
                        float4 a = x4[idx], wb = w4[idx];
                        d = fma((double)a.x, (double)wb.x, d);
                        d = fma((double)a.y, (double)wb.y, d);
                        d = fma((double)a.z, (double)wb.z, d);
                        d = fma((double)a.w, (double)wb.w, d);
                    }
#pragma unroll
                    for (int m = 1; m <= 8; m <<= 1) d += __shfl_xor(d, m);
                    const double s64 = wnorm64[k2] - 2.0 * d;
                    if (s64 < best || (s64 == best && k2 < bk)) { best = s64; bk = k2; }
                }
            }
            k = bk;   // uniform within group (same candidates, same fp64 values)
        }
        bestk[r] = k;
        if ((l & 15) == 0) {
            const int row = r0 + ((l >> 4) << 2) + r;
            out_idx[row] = (float)k;
            atomicAdd(&counts[k], 1);
        }
    }

    // ---- epilogue (per-wave): out_q + one-hot + loss ----
    double ls0 = 0.0, ls1 = 0.0, ls2 = 0.0, ls3 = 0.0;
#pragma unroll
    for (int rr = 0; rr < 16; ++rr) {
        const int k = __shfl(bestk[rr & 3], (rr >> 2) * 16);
        const int row = r0 + rr;
        float4 xv = ((const float4*)(x  + (size_t)row * DIM))[l];
        float4 qv = ((const float4*)(wT + (size_t)k  * DIM))[l];
        f32x4 o = {xv.x + (qv.x - xv.x), xv.y + (qv.y - xv.y),
                   xv.z + (qv.z - xv.z), xv.w + (qv.w - xv.w)};
        __builtin_nontemporal_store(o, (f32x4*)(out_q + (size_t)row * DIM) + l);
        double dx = (double)qv.x - (double)xv.x; ls0 = fma(dx, dx, ls0);
        dx = (double)qv.y - (double)xv.y; ls1 = fma(dx, dx, ls1);
        dx = (double)qv.z - (double)xv.z; ls2 = fma(dx, dx, ls2);
        dx = (double)qv.w - (double)xv.w; ls3 = fma(dx, dx, ls3);
        // one-hot zeros: coalesced f32x2 stores (512 contiguous B / instr)
        f32x2* er2 = (f32x2*)(out_enc + (size_t)row * KC);
        f32x2 z = {0.f, 0.f};
#pragma unroll
        for (int i = 0; i < 8; ++i)
            __builtin_nontemporal_store(z, er2 + i * 64 + l);
        // the 1.0: same lane that wrote the covering f32x2 (program order)
        if (l == ((k >> 1) & 63)) out_enc[(size_t)row * KC + k] = 1.0f;
    }

    double lsum = (ls0 + ls1) + (ls2 + ls3);
#pragma unroll
    for (int off = 32; off > 0; off >>= 1) lsum += __shfl_down(lsum, off);
    if (l == 0) wsum[wv] = lsum;
    __syncthreads();
    if (t == 0) {
        double s = 0.0;
#pragma unroll
        for (int i = 0; i < 8; ++i) s += wsum[i];
        atomicAdd(loss_sum, s);
    }
}

// ---------- finalize ----------
__global__ __launch_bounds__(1024) void final_kernel(const int* __restrict__ counts,
                                                     const double* __restrict__ loss_sum,
                                                     float* __restrict__ out_loss,
                                                     float* __restrict__ out_ppl) {
    const int t = threadIdx.x;
    double p = (double)counts[t] * (1.0 / 32768.0);
    double term = -p * log(p + 1e-10);
#pragma unroll
    for (int off = 32; off > 0; off >>= 1) term += __shfl_down(term, off);
    __shared__ double ws[16];
    if ((t & 63) == 0) ws[t >> 6] = term;
    __syncthreads();
    if (t == 0) {
        double s = 0.0;
        for (int i = 0; i < 16; ++i) s += ws[i];
        *out_ppl = (float)exp(s);
        *out_loss = (float)(1.25 * loss_sum[0] * (1.0 / 8388608.0));
    }
}

extern "C" void kernel_launch(void* const* d_in, const int* in_sizes, int n_in,
                              void* d_out, int out_size, void* d_ws, size_t ws_size,
                              hipStream_t stream) {
    const float* x = (const float*)d_in[0];   // [32,32,32,256] fp32
    const float* w = (const float*)d_in[1];   // [256,1024] fp32

    float* out = (float*)d_out;
    float* out_q    = out;                        // 8388608
    float* out_loss = out + 8388608;              // 1
    float* out_ppl  = out + 8388609;              // 1
    float* out_enc  = out + 8388610;              // 33554432
    float* out_idx  = out + 8388610 + 33554432;   // 32768

    char* wsb = (char*)d_ws;
    double* loss_sum = (double*)(wsb + 0);
    int*    counts   = (int*)(wsb + 64);          // 4096 B
    double* wnorm64  = (double*)(wsb + 4160);     // 8192 B
    float*  wnormf   = (float*)(wsb + 12352);     // 4096 B
    float*  wT       = (float*)(wsb + 16448);     // 1 MB
    uint4*  wph      = (uint4*)(wsb + 1065024);   // 512 KB

    (void)hipMemsetAsync(d_ws, 0, 4160, stream);  // loss_sum + counts

    prep_w<<<128, 256, 0, stream>>>(w, wph, wT);
    wnorm_kernel<<<4, 256, 0, stream>>>(wT, wnorm64, wnormf);
    vq_fused<<<256, 512, 0, stream>>>(x, (const char*)wph, wT, wnorm64, wnormf,
                                      out_q, out_idx, out_enc, counts, loss_sum);
    final_kernel<<<1, 1024, 0, stream>>>(counts, loss_sum, out_loss, out_ppl);
}